// Round 2
// baseline (201.382 us; speedup 1.0000x reference)
//
#include <hip/hip_runtime.h>

#define B_ROWS 524288
#define D_DIM 64
#define GRID 8192
#define BLOCK 256
// waves total = GRID*BLOCK/64 = 32768; each wave owns 16 consecutive rows:
// 32768 * 16 = 524288 = B_ROWS exactly -> NO per-thread loop, max TLP.

// clang ext-vector float4: required by __builtin_nontemporal_load (HIP's
// float4 is a struct-wrapped HIP_vector_type, which the builtin rejects).
typedef float floatx4 __attribute__((ext_vector_type(4)));

// 4 lanes per row: each lane loads 4 float4 chunks (16 floats) of its row.
// Label gather is issued BEFORE the x loads so the dependent table gathers
// (linear_p/bias_p/centers, L2-resident) overlap the streaming x reads.
// x loads are nontemporal (read-once, 134 MB) to avoid thrashing L2 for the
// small tables. Epilogue duplicated across the 4 lanes of a group
// (same-address gathers broadcast); corrected by 0.25 in finalize.
__global__ __launch_bounds__(BLOCK) void mcl_main(
    const float* __restrict__ x,
    const int* __restrict__ labels,
    const float* __restrict__ lin_w,
    const float* __restrict__ lin_b,
    const float* __restrict__ linear_p,   // (1000,1,3)
    const float* __restrict__ bias_p,     // (1000,3)
    const float* __restrict__ centers,    // (1000,3,1)
    float* __restrict__ partials)
{
    const int tid  = blockIdx.x * BLOCK + threadIdx.x;
    const int lane = threadIdx.x & 63;
    const int sub  = lane & 3;              // position within 4-lane row group
    const int row  = (tid >> 6) * 16 + (lane >> 2);

    // --- independent gather chain: issue first so it overlaps the x stream ---
    const int lab = labels[row];

    // --- streaming x reads (nontemporal: read-once) ---
    const floatx4* xr = (const floatx4*)(x + (size_t)row * D_DIM);
    const floatx4 x0 = __builtin_nontemporal_load(xr + sub + 0);
    const floatx4 x1 = __builtin_nontemporal_load(xr + sub + 4);
    const floatx4 x2 = __builtin_nontemporal_load(xr + sub + 8);
    const floatx4 x3 = __builtin_nontemporal_load(xr + sub + 12);

    // table gathers (depend only on lab; in flight while x FMAs wait)
    const float p0 = linear_p[lab * 3 + 0];
    const float p1 = linear_p[lab * 3 + 1];
    const float p2 = linear_p[lab * 3 + 2];
    const float b0 = bias_p[lab * 3 + 0];
    const float b1 = bias_p[lab * 3 + 1];
    const float b2 = bias_p[lab * 3 + 2];
    const float c0 = centers[lab * 3 + 0];
    const float c1 = centers[lab * 3 + 1];
    const float c2 = centers[lab * 3 + 2];

    // lin_w is 64 floats, L2/L1-resident
    const floatx4 lw0 = ((const floatx4*)lin_w)[sub + 0];
    const floatx4 lw1 = ((const floatx4*)lin_w)[sub + 4];
    const floatx4 lw2 = ((const floatx4*)lin_w)[sub + 8];
    const floatx4 lw3 = ((const floatx4*)lin_w)[sub + 12];
    const float   lb  = lin_b[0];

    float sd = x0[0]*lw0[0] + x0[1]*lw0[1] + x0[2]*lw0[2] + x0[3]*lw0[3]
             + x1[0]*lw1[0] + x1[1]*lw1[1] + x1[2]*lw1[2] + x1[3]*lw1[3]
             + x2[0]*lw2[0] + x2[1]*lw2[1] + x2[2]*lw2[2] + x2[3]*lw2[3]
             + x3[0]*lw3[0] + x3[1]*lw3[1] + x3[2]*lw3[2] + x3[3]*lw3[3];
    float ss = (x0[0] + x0[1] + x0[2] + x0[3]) + (x1[0] + x1[1] + x1[2] + x1[3])
             + (x2[0] + x2[1] + x2[2] + x2[3]) + (x3[0] + x3[1] + x3[2] + x3[3]);
    float sq = x0[0]*x0[0] + x0[1]*x0[1] + x0[2]*x0[2] + x0[3]*x0[3]
             + x1[0]*x1[0] + x1[1]*x1[1] + x1[2]*x1[2] + x1[3]*x1[3]
             + x2[0]*x2[0] + x2[1]*x2[1] + x2[2]*x2[2] + x2[3]*x2[3]
             + x3[0]*x3[0] + x3[1]*x3[1] + x3[2]*x3[2] + x3[3]*x3[3];

    // 2-stage butterfly within the 4-lane group (compiles to DPP quad-perm)
    #pragma unroll
    for (int off = 1; off < 4; off <<= 1) {
        sd += __shfl_xor(sd, off, 64);
        ss += __shfl_xor(ss, off, 64);
        sq += __shfl_xor(sq, off, 64);
    }

    // Epilogue on all lanes (4-way duplicated; corrected by 0.25 at the end)
    const float maps = sd + lb;

    const float l0 = maps * p0 + b0;
    const float l1 = maps * p1 + b1;
    const float l2 = maps * p2 + b2;

    const float m  = fmaxf(l0, fmaxf(l1, l2));
    const float e0 = __expf(l0 - m);
    const float e1 = __expf(l1 - m);
    const float e2 = __expf(l2 - m);
    const float rdenom = __builtin_amdgcn_rcpf(e0 + e1 + e2);

    const float dD = (float)D_DIM;
    const float s0 = sq - 2.0f * c0 * ss + dD * c0 * c0;
    const float s1 = sq - 2.0f * c1 * ss + dD * c1 * c1;
    const float s2 = sq - 2.0f * c2 * ss + dD * c2 * c2;

    float acc = (e0 * s0 + e1 * s1 + e2 * s2) * rdenom;

    // wave reduction (each row counted 4x; corrected in finalize)
    #pragma unroll
    for (int off = 1; off < 64; off <<= 1)
        acc += __shfl_xor(acc, off, 64);

    __shared__ float waveSums[BLOCK / 64];
    if (lane == 0) waveSums[threadIdx.x >> 6] = acc;
    __syncthreads();
    if (threadIdx.x == 0) {
        float s = waveSums[0] + waveSums[1] + waveSums[2] + waveSums[3];
        partials[blockIdx.x] = s;   // plain store; reducer kernel consumes
    }
}

// Single-block finalize: sum GRID partials, scale, overwrite out (no init needed).
__global__ __launch_bounds__(BLOCK) void mcl_finalize(
    const float* __restrict__ partials, float* __restrict__ out)
{
    float acc = 0.0f;
    #pragma unroll
    for (int i = 0; i < GRID / BLOCK; ++i)          // 32 strided reads
        acc += partials[i * BLOCK + threadIdx.x];

    const int lane = threadIdx.x & 63;
    #pragma unroll
    for (int off = 1; off < 64; off <<= 1)
        acc += __shfl_xor(acc, off, 64);

    __shared__ float waveSums[BLOCK / 64];
    if (lane == 0) waveSums[threadIdx.x >> 6] = acc;
    __syncthreads();
    if (threadIdx.x == 0) {
        float s = waveSums[0] + waveSums[1] + waveSums[2] + waveSums[3];
        out[0] = s * (0.25f / (float)B_ROWS);
    }
}

extern "C" void kernel_launch(void* const* d_in, const int* in_sizes, int n_in,
                              void* d_out, int out_size, void* d_ws, size_t ws_size,
                              hipStream_t stream) {
    const float* x        = (const float*)d_in[0];
    const int*   labels   = (const int*)d_in[1];
    const float* lin_w    = (const float*)d_in[2];
    const float* lin_b    = (const float*)d_in[3];
    const float* linear_p = (const float*)d_in[4];
    const float* bias_p   = (const float*)d_in[5];
    const float* centers  = (const float*)d_in[6];
    float* out      = (float*)d_out;
    float* partials = (float*)d_ws;

    mcl_main<<<dim3(GRID), dim3(BLOCK), 0, stream>>>(
        x, labels, lin_w, lin_b, linear_p, bias_p, centers, partials);
    mcl_finalize<<<dim3(1), dim3(BLOCK), 0, stream>>>(partials, out);
}